// Round 3
// baseline (1510.876 us; speedup 1.0000x reference)
//
#include <hip/hip_runtime.h>
#include <hip/hip_bf16.h>

typedef __bf16 bf16_t;
typedef bf16_t bf16x8 __attribute__((ext_vector_type(8)));
typedef float f32x4 __attribute__((ext_vector_type(4)));
typedef float f32x4v __attribute__((ext_vector_type(4)));

#define L_NUM 3
#define E_NUM 4
#define D_DIM 1024
#define B_ROWS 32768
#define BT 64
#define TPB 512
#define NBLK (B_ROWS / BT)   // 512
#define N1 272               // 256 V-cols + 4 gating cols + 12 zero pad

#define VT_ELEMS (L_NUM * N1 * D_DIM)            // 835584
#define UT_ELEMS (L_NUM * D_DIM * 256)           // 786432
#define CB_ELEMS (L_NUM * E_NUM * 64 * 64)       // 49152
#define GWS_BYTE_OFF ((VT_ELEMS + UT_ELEMS + CB_ELEMS) * 2)  // 3342336

#define MFMA16(a, b, c) __builtin_amdgcn_mfma_f32_16x16x32_bf16((a), (b), (c), 0, 0, 0)

__device__ __forceinline__ ushort f2b(float f) {
  union { float f; unsigned u; } x; x.f = f;
  unsigned r = (x.u + 0x7fffu + ((x.u >> 16) & 1u)) >> 16;  // RNE
  return (ushort)r;
}
__device__ __forceinline__ float b2f(ushort h) {
  union { unsigned u; float f; } x; x.u = ((unsigned)h) << 16;
  return x.f;
}
__device__ __forceinline__ float u2f_lo(unsigned u) {
  union { unsigned u; float f; } x; x.u = u << 16; return x.f;
}
__device__ __forceinline__ float u2f_hi(unsigned u) {
  union { unsigned u; float f; } x; x.u = u & 0xffff0000u; return x.f;
}
__device__ __forceinline__ float tanh_fast(float x) {
  float cx = fminf(fmaxf(x, -15.f), 15.f);
  float e = __expf(2.f * cx);
  return (e - 1.f) / (e + 1.f);
}
// XOR-swizzled element offset within a [ROWS][COLS] bf16 tile (16B-chunk swizzle).
__device__ __forceinline__ int swz(int r, int c, int cols) {
  return r * cols + ((((c >> 3) ^ (r & 7)) << 3) | (c & 7));
}

// ---------------- weight prepack: f32 -> bf16, B^T ([N][K]) layouts ----------------

__global__ void pack_vt_kernel(const float* __restrict__ V, const float* __restrict__ gw,
                               ushort* __restrict__ vt) {
  int idx = blockIdx.x * 256 + threadIdx.x;
  if (idx >= VT_ELEMS) return;
  int d = idx & (D_DIM - 1);
  int n = (idx >> 10) % N1;
  int l = idx / (N1 * D_DIM);
  float val = 0.f;
  if (n < 256) {
    int e = n >> 6, r = n & 63;
    val = V[(((l * E_NUM + e) * D_DIM) + d) * 64 + r];   // Vt[l][e*64+r][d] = V[l,e,d,r]
  } else if (n < 260) {
    val = gw[(n - 256) * D_DIM + d];                     // gating cols
  }
  vt[idx] = f2b(val);
}

__global__ void pack_ut_kernel(const float* __restrict__ U, ushort* __restrict__ ut) {
  int idx = blockIdx.x * 256 + threadIdx.x;
  if (idx >= UT_ELEMS) return;
  int er = idx & 255;
  int d = (idx >> 8) & (D_DIM - 1);
  int l = idx >> 18;
  int e = er >> 6, r = er & 63;
  ut[idx] = f2b(U[((l * E_NUM + e) * D_DIM + d) * 64 + r]);  // Ut[l][d][e*64+r]
}

__global__ void pack_cb_kernel(const float* __restrict__ C, ushort* __restrict__ cb) {
  int idx = blockIdx.x * 256 + threadIdx.x;
  if (idx >= CB_ELEMS) return;
  cb[idx] = f2b(C[idx]);   // C[l,e,r,s] already is Bt[n=r][k=s]
}

// ---------------- fused 3-layer CrossNet: each block owns 64 rows end-to-end ----------------
// LDS = 160 KiB exactly (1 block/CU); launch_bounds(512,2) -> 256 VGPR+AGPR budget, no spills.

__global__ __launch_bounds__(TPB, 2) void crossnet_fused(
    const float* __restrict__ inputs, const float* __restrict__ bias,
    const ushort* __restrict__ Vt, const ushort* __restrict__ Ut,
    const ushort* __restrict__ Cb, float* __restrict__ gws,
    float* __restrict__ out) {
  __shared__ ushort xl[BT * 1024];   // 131072 B, swizzled
  __shared__ ushort t1s[BT * 256];   // 32768 B, swizzled

  const int tid = threadIdx.x;
  const int wave = tid >> 6;
  const int lane = tid & 63;
  const int l15 = lane & 15;
  const int quad = lane >> 4;
  const int r7 = l15 & 7;
  const long rowbase = (long)blockIdx.x * BT;
  float* gwb = gws + (long)blockIdx.x * (BT * E_NUM);

  // ---- stage inputs -> xl (bf16, swizzled; nontemporal float4 loads) ----
  #pragma unroll 8
  for (int i = 0; i < 32; ++i) {
    int idx = tid + i * TPB;       // float4 index within [64][256]
    int r = idx >> 8;
    int c4 = idx & 255;
    f32x4v v = __builtin_nontemporal_load(((const f32x4v*)(inputs + (rowbase + r) * D_DIM)) + c4);
    ushort4 h;
    h.x = f2b(v.x); h.y = f2b(v.y); h.z = f2b(v.z); h.w = f2b(v.w);
    int off = r * 1024 + ((((c4 >> 1) ^ (r & 7)) << 3) | ((c4 & 1) << 2));
    *(ushort4*)&xl[off] = h;
  }
  __syncthreads();

  // ---- x0 packed bf16 (2 rows/reg) at this wave's GEMM2 C-layout positions: 64 VGPRs ----
  unsigned x0p[2][4][4][2];
  #pragma unroll
  for (int half = 0; half < 2; ++half)
    #pragma unroll
    for (int nt = 0; nt < 4; ++nt) {
      int col = wave * 128 + half * 64 + nt * 16 + l15;
      #pragma unroll
      for (int m = 0; m < 4; ++m)
        #pragma unroll
        for (int pr = 0; pr < 2; ++pr) {
          int r0 = m * 16 + quad * 4 + 2 * pr;
          unsigned lo = xl[swz(r0, col, 1024)];
          unsigned hi = xl[swz(r0 + 1, col, 1024)];
          x0p[half][nt][m][pr] = lo | (hi << 16);
        }
    }

  const f32x4 zf = {0.f, 0.f, 0.f, 0.f};
  const int e = wave >> 1;   // expert (phase C)
  const int nh = wave & 1;   // 32-col half of this expert's 64 outputs

  for (int l = 0; l < L_NUM; ++l) {
    const ushort* vtl = Vt + l * N1 * D_DIM;
    const ushort* utl = Ut + l * D_DIM * 256;
    const ushort* cbl = Cb + l * E_NUM * 64 * 64;

    // ============ Phase A: T1[64,272] = xl[64,1024] @ [V|gw]^T (B double-buffered) ============
    f32x4 acc1[2][4];
    f32x4 accg[4];
    #pragma unroll
    for (int m = 0; m < 4; ++m) { acc1[0][m] = zf; acc1[1][m] = zf; }

    const ushort* vb0 = vtl + (wave * 32 + l15) * D_DIM + quad * 8;
    const ushort* vb1 = vb0 + 16 * D_DIM;

    if (wave == 7) {  // wave 7 also computes the gating tile (cols 256..271)
      #pragma unroll
      for (int m = 0; m < 4; ++m) accg[m] = zf;
      const ushort* vb2 = vtl + (256 + l15) * D_DIM + quad * 8;
      bf16x8 b0[2][2], b1[2][2], b2[2][2];   // [slot][i]
      b0[0][0] = *(const bf16x8*)(vb0);      b0[0][1] = *(const bf16x8*)(vb0 + 32);
      b1[0][0] = *(const bf16x8*)(vb1);      b1[0][1] = *(const bf16x8*)(vb1 + 32);
      b2[0][0] = *(const bf16x8*)(vb2);      b2[0][1] = *(const bf16x8*)(vb2 + 32);
      #pragma unroll
      for (int g = 0; g < 16; ++g) {
        const int s = g & 1, ns = s ^ 1;
        if (g < 15) {
          int t0 = 2 * g + 2;
          b0[ns][0] = *(const bf16x8*)(vb0 + t0 * 32); b0[ns][1] = *(const bf16x8*)(vb0 + t0 * 32 + 32);
          b1[ns][0] = *(const bf16x8*)(vb1 + t0 * 32); b1[ns][1] = *(const bf16x8*)(vb1 + t0 * 32 + 32);
          b2[ns][0] = *(const bf16x8*)(vb2 + t0 * 32); b2[ns][1] = *(const bf16x8*)(vb2 + t0 * 32 + 32);
        }
        #pragma unroll
        for (int i = 0; i < 2; ++i) {
          int t = 2 * g + i;
          int ch = ((4 * t + quad) ^ r7) << 3;
          #pragma unroll
          for (int m = 0; m < 4; ++m) {
            bf16x8 a = *(const bf16x8*)&xl[(m * 16 + l15) * 1024 + ch];
            acc1[0][m] = MFMA16(a, b0[s][i], acc1[0][m]);
            acc1[1][m] = MFMA16(a, b1[s][i], acc1[1][m]);
            accg[m]    = MFMA16(a, b2[s][i], accg[m]);
          }
        }
      }
    } else {
      bf16x8 b0[2][2], b1[2][2];
      b0[0][0] = *(const bf16x8*)(vb0);      b0[0][1] = *(const bf16x8*)(vb0 + 32);
      b1[0][0] = *(const bf16x8*)(vb1);      b1[0][1] = *(const bf16x8*)(vb1 + 32);
      #pragma unroll
      for (int g = 0; g < 16; ++g) {
        const int s = g & 1, ns = s ^ 1;
        if (g < 15) {
          int t0 = 2 * g + 2;
          b0[ns][0] = *(const bf16x8*)(vb0 + t0 * 32); b0[ns][1] = *(const bf16x8*)(vb0 + t0 * 32 + 32);
          b1[ns][0] = *(const bf16x8*)(vb1 + t0 * 32); b1[ns][1] = *(const bf16x8*)(vb1 + t0 * 32 + 32);
        }
        #pragma unroll
        for (int i = 0; i < 2; ++i) {
          int t = 2 * g + i;
          int ch = ((4 * t + quad) ^ r7) << 3;
          #pragma unroll
          for (int m = 0; m < 4; ++m) {
            bf16x8 a = *(const bf16x8*)&xl[(m * 16 + l15) * 1024 + ch];
            acc1[0][m] = MFMA16(a, b0[s][i], acc1[0][m]);
            acc1[1][m] = MFMA16(a, b1[s][i], acc1[1][m]);
          }
        }
      }
    }

    // epilogue: v1 = tanh(T1) -> t1s; wave 7 softmax -> gwb (global scratch)
    #pragma unroll
    for (int tt = 0; tt < 2; ++tt) {
      int ncol = wave * 32 + tt * 16 + l15;
      #pragma unroll
      for (int m = 0; m < 4; ++m)
        #pragma unroll
        for (int rg = 0; rg < 4; ++rg) {
          int row = m * 16 + quad * 4 + rg;
          t1s[swz(row, ncol, 256)] = f2b(tanh_fast(acc1[tt][m][rg]));
        }
    }
    if (wave == 7) {
      #pragma unroll
      for (int m = 0; m < 4; ++m)
        #pragma unroll
        for (int rg = 0; rg < 4; ++rg) {
          float g = accg[m][rg];                 // logit for expert l15 (valid l15<4)
          float mx = fmaxf(g, __shfl_xor(g, 1));
          mx = fmaxf(mx, __shfl_xor(mx, 2));
          float ex = __expf(g - mx);
          float s = ex + __shfl_xor(ex, 1);
          s = s + __shfl_xor(s, 2);
          if (l15 < 4) {
            int row = m * 16 + quad * 4 + rg;
            gwb[row * 4 + l15] = ex / s;
          }
        }
    }
    // prefetch phase-C B fragments (completes during barrier drain)
    const ushort* cbp = cbl + (e * 64 + nh * 32 + l15) * 64 + quad * 8;
    bf16x8 cbf[2][2];   // [tt][t]
    cbf[0][0] = *(const bf16x8*)(cbp);
    cbf[0][1] = *(const bf16x8*)(cbp + 32);
    cbf[1][0] = *(const bf16x8*)(cbp + 16 * 64);
    cbf[1][1] = *(const bf16x8*)(cbp + 16 * 64 + 32);
    __syncthreads();   // (1) t1s(v1) + gate visible

    // ============ Phase C: block-diag v2 = tanh(C @ v1), w = gate*v2 ============
    f32x4 acc2[2][4];
    #pragma unroll
    for (int m = 0; m < 4; ++m) { acc2[0][m] = zf; acc2[1][m] = zf; }
    #pragma unroll
    for (int t = 0; t < 2; ++t) {
      int ch = ((8 * e + 4 * t + quad) ^ r7) << 3;
      #pragma unroll
      for (int m = 0; m < 4; ++m) {
        bf16x8 a = *(const bf16x8*)&t1s[(m * 16 + l15) * 256 + ch];
        acc2[0][m] = MFMA16(a, cbf[0][t], acc2[0][m]);
        acc2[1][m] = MFMA16(a, cbf[1][t], acc2[1][m]);
      }
    }
    float g8[4][4];
    #pragma unroll
    for (int m = 0; m < 4; ++m)
      #pragma unroll
      for (int rg = 0; rg < 4; ++rg)
        g8[m][rg] = gwb[(m * 16 + quad * 4 + rg) * 4 + e];
    __syncthreads();   // (2) all v1 reads done -> safe to overwrite t1s
    #pragma unroll
    for (int tt = 0; tt < 2; ++tt) {
      int ncol = e * 64 + nh * 32 + tt * 16 + l15;
      #pragma unroll
      for (int m = 0; m < 4; ++m)
        #pragma unroll
        for (int rg = 0; rg < 4; ++rg) {
          int row = m * 16 + quad * 4 + rg;
          t1s[swz(row, ncol, 256)] = f2b(g8[m][rg] * tanh_fast(acc2[tt][m][rg]));
        }
    }
    // prefetch GEMM2 half-0 group-0 B fragments (completes during barrier drain)
    const ushort* ub = utl + (wave * 128 + l15) * 256 + quad * 8;
    bf16x8 ubuf[2][4];
    #pragma unroll
    for (int nt = 0; nt < 4; ++nt) ubuf[0][nt] = *(const bf16x8*)(ub + nt * 16 * 256);
    __syncthreads();   // (3) w complete

    // ============ Phase D: S[64,1024] = w[64,256] @ Ut^T (two 64-col halves) ============
    #pragma unroll
    for (int half = 0; half < 2; ++half) {
      const ushort* ubh = ub + half * 64 * 256;
      if (half == 1) {
        #pragma unroll
        for (int nt = 0; nt < 4; ++nt) ubuf[0][nt] = *(const bf16x8*)(ubh + nt * 16 * 256);
      }
      f32x4 acc3[4][4];
      #pragma unroll
      for (int nt = 0; nt < 4; ++nt)
        #pragma unroll
        for (int m = 0; m < 4; ++m) acc3[nt][m] = zf;
      #pragma unroll
      for (int g = 0; g < 8; ++g) {
        const int s = g & 1, ns = s ^ 1;
        if (g < 7) {
          #pragma unroll
          for (int nt = 0; nt < 4; ++nt)
            ubuf[ns][nt] = *(const bf16x8*)(ubh + nt * 16 * 256 + (g + 1) * 32);
        }
        int ch = ((4 * g + quad) ^ r7) << 3;
        #pragma unroll
        for (int m = 0; m < 4; ++m) {
          bf16x8 a = *(const bf16x8*)&t1s[(m * 16 + l15) * 256 + ch];
          #pragma unroll
          for (int nt = 0; nt < 4; ++nt)
            acc3[nt][m] = MFMA16(a, ubuf[s][nt], acc3[nt][m]);
        }
      }
      // epilogue: x_new = x_l + x0*(S + bias[l])
      #pragma unroll
      for (int nt = 0; nt < 4; ++nt) {
        int col = wave * 128 + half * 64 + nt * 16 + l15;
        float bv = bias[l * D_DIM + col];
        #pragma unroll
        for (int m = 0; m < 4; ++m)
          #pragma unroll
          for (int pr = 0; pr < 2; ++pr) {
            unsigned u = x0p[half][nt][m][pr];
            int r0 = m * 16 + quad * 4 + 2 * pr;
            float xe = b2f(xl[swz(r0, col, 1024)]) + u2f_lo(u) * (acc3[nt][m][2 * pr] + bv);
            float xo = b2f(xl[swz(r0 + 1, col, 1024)]) + u2f_hi(u) * (acc3[nt][m][2 * pr + 1] + bv);
            if (l < 2) {
              xl[swz(r0, col, 1024)] = f2b(xe);
              xl[swz(r0 + 1, col, 1024)] = f2b(xo);
            } else {
              __builtin_nontemporal_store(xe, out + (rowbase + r0) * D_DIM + col);
              __builtin_nontemporal_store(xo, out + (rowbase + r0 + 1) * D_DIM + col);
            }
          }
      }
    }
    __syncthreads();   // (4) xl updated; t1s free for next layer
  }
}

extern "C" void kernel_launch(void* const* d_in, const int* in_sizes, int n_in,
                              void* d_out, int out_size, void* d_ws, size_t ws_size,
                              hipStream_t stream) {
  (void)in_sizes; (void)n_in; (void)out_size; (void)ws_size;
  const float* inputs = (const float*)d_in[0];
  const float* U      = (const float*)d_in[1];
  const float* V      = (const float*)d_in[2];
  const float* C      = (const float*)d_in[3];
  const float* gw     = (const float*)d_in[4];
  const float* bias   = (const float*)d_in[5];
  float* out = (float*)d_out;

  ushort* vt = (ushort*)d_ws;          // 3*272*1024 bf16
  ushort* ut = vt + VT_ELEMS;          // 3*1024*256 bf16
  ushort* cb = ut + UT_ELEMS;          // 3*4*64*64  bf16
  float* gws = (float*)((char*)d_ws + GWS_BYTE_OFF);  // 512 blocks * 256 floats

  pack_vt_kernel<<<(VT_ELEMS + 255) / 256, 256, 0, stream>>>(V, gw, vt);
  pack_ut_kernel<<<(UT_ELEMS + 255) / 256, 256, 0, stream>>>(U, ut);
  pack_cb_kernel<<<(CB_ELEMS + 255) / 256, 256, 0, stream>>>(C, cb);

  crossnet_fused<<<NBLK, TPB, 0, stream>>>(inputs, bias, vt, ut, cb, gws, out);
}

// Round 4
// 912.378 us; speedup vs baseline: 1.6560x; 1.6560x over previous
//
#include <hip/hip_runtime.h>
#include <hip/hip_bf16.h>

typedef __bf16 bf16_t;
typedef bf16_t bf16x8 __attribute__((ext_vector_type(8)));
typedef float f32x4 __attribute__((ext_vector_type(4)));
typedef ushort us8 __attribute__((ext_vector_type(8)));

#define L_NUM 3
#define E_NUM 4
#define D_DIM 1024
#define B_ROWS 32768
#define BT 32
#define TPB 512
#define NBLK1 (B_ROWS / BT)        // 1024
#define N1 272                     // 256 V-cols + 4 gating cols + 12 zero pad

#define VT_ELEMS (L_NUM * N1 * D_DIM)            // 835584
#define UT_ELEMS (L_NUM * D_DIM * 256)           // 786432
#define CB_ELEMS (L_NUM * E_NUM * 64 * 64)       // 49152
// ws layout (bytes)
#define GWS_OFF ((VT_ELEMS + UT_ELEMS + CB_ELEMS) * 2)      // 3342336
#define W_OFF   (GWS_OFF + NBLK1 * 128 * 4)                 // + 512 KB
#define XB1_OFF (W_OFF + B_ROWS * 256 * 2)                  // + 16 MB
#define XB2_OFF (XB1_OFF + B_ROWS * D_DIM * 2)              // + 64 MB

#define MFMA16(a, b, c) __builtin_amdgcn_mfma_f32_16x16x32_bf16((a), (b), (c), 0, 0, 0)

__device__ __forceinline__ ushort f2b(float f) {
  union { float f; unsigned u; } x; x.f = f;
  unsigned r = (x.u + 0x7fffu + ((x.u >> 16) & 1u)) >> 16;  // RNE
  return (ushort)r;
}
__device__ __forceinline__ float b2f(ushort h) {
  union { unsigned u; float f; } x; x.u = ((unsigned)h) << 16;
  return x.f;
}
__device__ __forceinline__ float tanh_fast(float x) {
  float cx = fminf(fmaxf(x, -15.f), 15.f);
  float e = __expf(2.f * cx);
  return (e - 1.f) / (e + 1.f);
}

// ---------------- weight prepack: f32 -> bf16, B^T ([N][K]) layouts ----------------

__global__ void pack_vt_kernel(const float* __restrict__ V, const float* __restrict__ gw,
                               ushort* __restrict__ vt) {
  int idx = blockIdx.x * 256 + threadIdx.x;
  if (idx >= VT_ELEMS) return;
  int d = idx & (D_DIM - 1);
  int n = (idx >> 10) % N1;
  int l = idx / (N1 * D_DIM);
  float val = 0.f;
  if (n < 256) {
    int e = n >> 6, r = n & 63;
    val = V[(((l * E_NUM + e) * D_DIM) + d) * 64 + r];   // Vt[l][e*64+r][d] = V[l,e,d,r]
  } else if (n < 260) {
    val = gw[(n - 256) * D_DIM + d];                     // gating cols
  }
  vt[idx] = f2b(val);
}

__global__ void pack_ut_kernel(const float* __restrict__ U, ushort* __restrict__ ut) {
  int idx = blockIdx.x * 256 + threadIdx.x;
  if (idx >= UT_ELEMS) return;
  int er = idx & 255;
  int d = (idx >> 8) & (D_DIM - 1);
  int l = idx >> 18;
  int e = er >> 6, r = er & 63;
  ut[idx] = f2b(U[((l * E_NUM + e) * D_DIM + d) * 64 + r]);  // Ut[l][d][e*64+r]
}

__global__ void pack_cb_kernel(const float* __restrict__ C, ushort* __restrict__ cb) {
  int idx = blockIdx.x * 256 + threadIdx.x;
  if (idx >= CB_ELEMS) return;
  cb[idx] = f2b(C[idx]);   // C[l,e,r,s] already is Bt[n=r][k=s]
}

// ================= K1: w = gate (.) tanh(C . tanh(x @ V^T)) for one layer =================
// LDS exactly 80 KB -> 2 blocks/CU (16 waves). No persistent per-thread state -> no spills.

__global__ __launch_bounds__(TPB, 4) void k1_vcw(
    const void* __restrict__ xin, int in_f32,
    const ushort* __restrict__ vtl, const ushort* __restrict__ cbl,
    float* __restrict__ gws, ushort* __restrict__ wout) {
  __shared__ ushort xtile[BT * 1024];   // 65536 B, swizzled 16B chunks
  __shared__ ushort t1s[BT * 256];      // 16384 B, swizzled

  const int tid = threadIdx.x;
  const int wave = tid >> 6;
  const int lane = tid & 63;
  const int l15 = lane & 15;
  const int quad = lane >> 4;
  const int r7 = l15 & 7;
  const long rowbase = (long)blockIdx.x * BT;
  float* gwb = gws + (long)blockIdx.x * 128;

  // ---- stage x-tile -> LDS bf16 swizzled ----
  if (in_f32) {
    const float* xf = (const float*)xin;
    #pragma unroll
    for (int i = 0; i < 16; ++i) {
      int idx = tid + i * TPB;          // float4 index within [32][256]
      int r = idx >> 8, c4 = idx & 255;
      float4 v = ((const float4*)(xf + (rowbase + r) * D_DIM))[c4];
      ushort4 h;
      h.x = f2b(v.x); h.y = f2b(v.y); h.z = f2b(v.z); h.w = f2b(v.w);
      int off = r * 1024 + ((((c4 >> 1) ^ (r & 7)) << 3) | ((c4 & 1) << 2));
      *(ushort4*)&xtile[off] = h;
    }
  } else {
    const ushort* xb = (const ushort*)xin;
    #pragma unroll
    for (int i = 0; i < 8; ++i) {
      int idx = tid + i * TPB;          // ushort8 index within [32][128]
      int r = idx >> 7, c8 = idx & 127;
      us8 v = *(const us8*)(xb + (rowbase + r) * D_DIM + c8 * 8);
      *(us8*)&xtile[r * 1024 + ((c8 ^ (r & 7)) << 3)] = v;
    }
  }
  __syncthreads();

  const f32x4 zf = {0.f, 0.f, 0.f, 0.f};

  // ---- phase A: T1[32,272] = x[32,1024] @ [V|gw]^T; wave w covers cols w*32..w*32+32 ----
  f32x4 acc1[2][2];
  acc1[0][0] = zf; acc1[0][1] = zf; acc1[1][0] = zf; acc1[1][1] = zf;
  const ushort* vb0 = vtl + (wave * 32 + l15) * D_DIM + quad * 8;
  const ushort* vb1 = vb0 + 16 * D_DIM;

  if (wave == 7) {   // wave 7 also does the gating tile (cols 256..271)
    f32x4 accg[2];
    accg[0] = zf; accg[1] = zf;
    const ushort* vb2 = vtl + (256 + l15) * D_DIM + quad * 8;
    #pragma unroll 2
    for (int t = 0; t < 32; ++t) {
      int ch = ((4 * t + quad) ^ r7) << 3;
      bf16x8 a0 = *(const bf16x8*)&xtile[l15 * 1024 + ch];
      bf16x8 a1 = *(const bf16x8*)&xtile[(16 + l15) * 1024 + ch];
      bf16x8 b0 = *(const bf16x8*)(vb0 + t * 32);
      bf16x8 b1 = *(const bf16x8*)(vb1 + t * 32);
      bf16x8 b2 = *(const bf16x8*)(vb2 + t * 32);
      acc1[0][0] = MFMA16(a0, b0, acc1[0][0]);
      acc1[0][1] = MFMA16(a1, b0, acc1[0][1]);
      acc1[1][0] = MFMA16(a0, b1, acc1[1][0]);
      acc1[1][1] = MFMA16(a1, b1, acc1[1][1]);
      accg[0]    = MFMA16(a0, b2, accg[0]);
      accg[1]    = MFMA16(a1, b2, accg[1]);
    }
    // softmax over experts (lanes 0..3 hold experts 0..3 per row) -> gwb global scratch
    #pragma unroll
    for (int m = 0; m < 2; ++m)
      #pragma unroll
      for (int rg = 0; rg < 4; ++rg) {
        float g = accg[m][rg];
        float mx = fmaxf(g, __shfl_xor(g, 1));
        mx = fmaxf(mx, __shfl_xor(mx, 2));
        float ex = __expf(g - mx);
        float s = ex + __shfl_xor(ex, 1);
        s = s + __shfl_xor(s, 2);
        if (l15 < 4) gwb[(m * 16 + quad * 4 + rg) * 4 + l15] = ex / s;
      }
  } else {
    #pragma unroll 2
    for (int t = 0; t < 32; ++t) {
      int ch = ((4 * t + quad) ^ r7) << 3;
      bf16x8 a0 = *(const bf16x8*)&xtile[l15 * 1024 + ch];
      bf16x8 a1 = *(const bf16x8*)&xtile[(16 + l15) * 1024 + ch];
      bf16x8 b0 = *(const bf16x8*)(vb0 + t * 32);
      bf16x8 b1 = *(const bf16x8*)(vb1 + t * 32);
      acc1[0][0] = MFMA16(a0, b0, acc1[0][0]);
      acc1[0][1] = MFMA16(a1, b0, acc1[0][1]);
      acc1[1][0] = MFMA16(a0, b1, acc1[1][0]);
      acc1[1][1] = MFMA16(a1, b1, acc1[1][1]);
    }
  }

  // v1 = tanh(T1) -> t1s (swizzled)
  #pragma unroll
  for (int tt = 0; tt < 2; ++tt) {
    int ncol = wave * 32 + tt * 16 + l15;
    #pragma unroll
    for (int m = 0; m < 2; ++m)
      #pragma unroll
      for (int rg = 0; rg < 4; ++rg) {
        int row = m * 16 + quad * 4 + rg;
        int c = ncol;
        t1s[row * 256 + ((((c >> 3) ^ (row & 7)) << 3) | (c & 7))] =
            f2b(tanh_fast(acc1[tt][m][rg]));
      }
  }
  __syncthreads();

  // ---- phase C: per-expert 64x64, w = gate (.) tanh(C @ v1) -> global ----
  const int e = wave >> 1;
  const int nh = wave & 1;
  f32x4 acc2[2][2];
  acc2[0][0] = zf; acc2[0][1] = zf; acc2[1][0] = zf; acc2[1][1] = zf;
  const ushort* cb0 = cbl + (e * 64 + nh * 32 + l15) * 64 + quad * 8;
  const ushort* cb1 = cb0 + 16 * 64;
  #pragma unroll
  for (int t = 0; t < 2; ++t) {
    int ch = ((8 * e + 4 * t + quad) ^ r7) << 3;
    bf16x8 a0 = *(const bf16x8*)&t1s[l15 * 256 + ch];
    bf16x8 a1 = *(const bf16x8*)&t1s[(16 + l15) * 256 + ch];
    bf16x8 b0 = *(const bf16x8*)(cb0 + t * 32);
    bf16x8 b1 = *(const bf16x8*)(cb1 + t * 32);
    acc2[0][0] = MFMA16(a0, b0, acc2[0][0]);
    acc2[0][1] = MFMA16(a1, b0, acc2[0][1]);
    acc2[1][0] = MFMA16(a0, b1, acc2[1][0]);
    acc2[1][1] = MFMA16(a1, b1, acc2[1][1]);
  }
  #pragma unroll
  for (int tt = 0; tt < 2; ++tt) {
    int ncol = e * 64 + nh * 32 + tt * 16 + l15;
    #pragma unroll
    for (int m = 0; m < 2; ++m)
      #pragma unroll
      for (int rg = 0; rg < 4; ++rg) {
        int row = m * 16 + quad * 4 + rg;
        float g = gwb[row * 4 + e];
        wout[(rowbase + row) * 256 + ncol] = f2b(g * tanh_fast(acc2[tt][m][rg]));
      }
  }
}

// ================= K2: x_new = x_l + x0 (.) (w @ U^T + bias) for one layer =================
// Block: 32 rows x 512 cols. LDS 16 KB. Scattered epilogue ok: C-layout 32B chunks are
// L2-line-adjacent across nt (nt=0..3 spans 128B contiguous per row).

__global__ __launch_bounds__(TPB, 4) void k2_ures(
    const ushort* __restrict__ wbuf, const ushort* __restrict__ utl,
    const float* __restrict__ x0f, const void* __restrict__ xlin, int xl_bf16,
    const float* __restrict__ biasl, void* __restrict__ dst, int out_f32) {
  __shared__ ushort ws[BT * 256];   // 16384 B, swizzled

  const int tid = threadIdx.x;
  const int wave = tid >> 6;
  const int lane = tid & 63;
  const int l15 = lane & 15;
  const int quad = lane >> 4;
  const int r7 = l15 & 7;
  const int rt = blockIdx.x >> 1;
  const int colbase = (blockIdx.x & 1) * 512;
  const long rowbase = (long)rt * BT;

  // stage w-tile [32][256] bf16 -> LDS swizzled (coalesced 16B loads)
  #pragma unroll
  for (int i = 0; i < 2; ++i) {
    int idx = tid + i * TPB;          // ushort8 index within [32][32]
    int r = idx >> 5, c8 = idx & 31;
    us8 v = *(const us8*)(wbuf + (rowbase + r) * 256 + c8 * 8);
    *(us8*)&ws[r * 256 + ((c8 ^ (r & 7)) << 3)] = v;
  }
  __syncthreads();

  const f32x4 zf = {0.f, 0.f, 0.f, 0.f};
  f32x4 acc[4][2];
  #pragma unroll
  for (int nt = 0; nt < 4; ++nt) { acc[nt][0] = zf; acc[nt][1] = zf; }

  const ushort* ub = utl + (colbase + wave * 64 + l15) * 256 + quad * 8;
  #pragma unroll 2
  for (int t = 0; t < 8; ++t) {
    int ch = ((4 * t + quad) ^ r7) << 3;
    bf16x8 a0 = *(const bf16x8*)&ws[l15 * 256 + ch];
    bf16x8 a1 = *(const bf16x8*)&ws[(16 + l15) * 256 + ch];
    #pragma unroll
    for (int nt = 0; nt < 4; ++nt) {
      bf16x8 b = *(const bf16x8*)(ub + nt * 16 * 256 + t * 32);
      acc[nt][0] = MFMA16(a0, b, acc[nt][0]);
      acc[nt][1] = MFMA16(a1, b, acc[nt][1]);
    }
  }

  // epilogue: x_new = x_l + x0*(S + bias)
  const ushort* xlb = (const ushort*)xlin;
  #pragma unroll
  for (int nt = 0; nt < 4; ++nt) {
    int col = colbase + wave * 64 + nt * 16 + l15;
    float bv = biasl[col];
    #pragma unroll
    for (int m = 0; m < 2; ++m)
      #pragma unroll
      for (int rg = 0; rg < 4; ++rg) {
        int row = m * 16 + quad * 4 + rg;
        long gidx = (rowbase + row) * D_DIM + col;
        float x0v = x0f[gidx];
        float xlv = xl_bf16 ? b2f(xlb[gidx]) : x0v;
        float xn = xlv + x0v * (acc[nt][m][rg] + bv);
        if (out_f32) ((float*)dst)[gidx] = xn;
        else         ((ushort*)dst)[gidx] = f2b(xn);
      }
  }
}

extern "C" void kernel_launch(void* const* d_in, const int* in_sizes, int n_in,
                              void* d_out, int out_size, void* d_ws, size_t ws_size,
                              hipStream_t stream) {
  (void)in_sizes; (void)n_in; (void)out_size; (void)ws_size;
  const float* inputs = (const float*)d_in[0];
  const float* U      = (const float*)d_in[1];
  const float* V      = (const float*)d_in[2];
  const float* C      = (const float*)d_in[3];
  const float* gw     = (const float*)d_in[4];
  const float* bias   = (const float*)d_in[5];
  float* out = (float*)d_out;

  char* ws = (char*)d_ws;
  ushort* vt  = (ushort*)ws;                  // 3*272*1024 bf16
  ushort* ut  = vt + VT_ELEMS;                // 3*1024*256 bf16
  ushort* cb  = ut + UT_ELEMS;                // 3*4*64*64  bf16
  float*  gws = (float*)(ws + GWS_OFF);       // 1024 blocks * 128 f32
  ushort* wb  = (ushort*)(ws + W_OFF);        // 32768*256 bf16 (reused per layer)
  ushort* xb1 = (ushort*)(ws + XB1_OFF);      // 32768*1024 bf16
  ushort* xb2 = (ushort*)(ws + XB2_OFF);      // 32768*1024 bf16

  pack_vt_kernel<<<(VT_ELEMS + 255) / 256, 256, 0, stream>>>(V, gw, vt);
  pack_ut_kernel<<<(UT_ELEMS + 255) / 256, 256, 0, stream>>>(U, ut);
  pack_cb_kernel<<<(CB_ELEMS + 255) / 256, 256, 0, stream>>>(C, cb);

  const void* xl_cur = inputs;   // layer-1 x_l = x0 (f32)
  ushort* xb_next = xb1;
  for (int l = 0; l < L_NUM; ++l) {
    const ushort* vtl = vt + l * N1 * D_DIM;
    const ushort* utl = ut + l * D_DIM * 256;
    const ushort* cbl = cb + l * E_NUM * 64 * 64;
    int in_f32 = (l == 0);
    k1_vcw<<<NBLK1, TPB, 0, stream>>>(xl_cur, in_f32, vtl, cbl, gws, wb);
    int out_f32 = (l == L_NUM - 1);
    void* dst = out_f32 ? (void*)out : (void*)xb_next;
    k2_ures<<<NBLK1 * 2, TPB, 0, stream>>>(wb, utl, inputs, xl_cur, in_f32 ? 0 : 1,
                                           bias + l * D_DIM, dst, out_f32);
    xl_cur = xb_next;
    xb_next = (xb_next == xb1) ? xb2 : xb1;
  }
}